// Round 10
// baseline (59.790 us; speedup 1.0000x reference)
//
#include <hip/hip_runtime.h>

typedef __bf16 bf16x8 __attribute__((ext_vector_type(8)));
typedef float f32x4 __attribute__((ext_vector_type(4)));

__device__ __forceinline__ unsigned short f2bf(float f) {
  __bf16 h = (__bf16)f;
  return __builtin_bit_cast(unsigned short, h);
}

// Fire-and-forget global->LDS copy: 64 lanes x 4B, per-lane global source,
// wave-uniform LDS dest (base + lane*4).
__device__ __forceinline__ void gload_lds4(const float* g, unsigned int* lds) {
  typedef __attribute__((address_space(1))) void gv_t;
  typedef __attribute__((address_space(3))) void lv_t;
  __builtin_amdgcn_global_load_lds((gv_t*)g, (lv_t*)lds, 4, 0, 0);
}

// d_ws layout: [0, 24576) bytes: wsB bf16 fragment-ordered (12288 shorts)
//              [24576, 24832): bias (64 floats)
// wsB flat idx = (((di*4 + jblk)*2 + kstep)*64 + lane)*8 + i
//   c   = kstep*32 + 4*(lane>>4) + (i&3) + 16*(i>>2)
//   fch = jblk*16 + (lane&15)
__global__ __launch_bounds__(256) void prep_kernel(
    const float* __restrict__ conv_w, const float* __restrict__ gamma,
    const float* __restrict__ beta, const float* __restrict__ mean,
    const float* __restrict__ var, unsigned short* __restrict__ wsB,
    float* __restrict__ bias) {
  int idx = blockIdx.x * 256 + threadIdx.x;
  if (idx >= 12288) return;
  int di    = idx >> 12;
  int r     = idx & 4095;
  int jblk  = r >> 10;
  int r2    = r & 1023;
  int kstep = r2 >> 9;
  int r3    = r2 & 511;
  int lane  = r3 >> 3;
  int i     = r3 & 7;
  int c   = kstep * 32 + 4 * (lane >> 4) + (i & 3) + 16 * (i >> 2);
  int fch = jblk * 16 + (lane & 15);
  float s = gamma[fch] * rsqrtf(var[fch] + 1e-3f);
  float v = conv_w[((di * 3 + 0) * 64 + c) * 64 + fch]
          + conv_w[((di * 3 + 1) * 64 + c) * 64 + fch]
          + conv_w[((di * 3 + 2) * 64 + c) * 64 + fch];
  wsB[idx] = f2bf(v * s);
  if (idx < 64) bias[idx] = beta[idx] - mean[idx] * (gamma[idx] * rsqrtf(var[idx] + 1e-3f));
}

// Wave-autonomous (no __syncthreads). Each wave owns pxblks {2w,2w+1}.
// Sampling is staged global->LDS via global_load_lds (zero VGPR in flight):
// per (pxblk, kstep) half-chunk, 32 fire-and-forget loads stage 16px x
// {y_top,y_bot} x {xl(lane<32), xr(lane>=32)} rows of 32 fp32 channels, row
// stride 272B (16B-aligned, bank-balanced). Consume: vmcnt(0), per-lane
// ds_read_b128 of its fragment's 4 corners x 2 halves, 4-coeff combine,
// pack bf16 -> MFMA. Zero samples: sentinel skips issue; stale data x 0
// coeffs = 0. Canary: WRITE_SIZE ~= 33 MB (no spills).
__global__ __launch_bounds__(256, 3) void main_kernel(
    const float* __restrict__ fmap, const float* __restrict__ y2,
    const uint4* __restrict__ wsBq, const float* __restrict__ biasg,
    float* __restrict__ out) {
  __shared__ int4   s_addr4[384];          // (lt,rt,lb,rb) element offsets; x<0 = skip
  __shared__ float4 s_cf[384];             // (a_lt, a_rt, a_lb, a_rb)
  __shared__ unsigned int stage[4][32 * 68];  // per-wave: 32 rows x 272B

  const int t    = threadIdx.x;
  const int lane = t & 63;
  const int wave = t >> 6;
  // XCD swizzle: pin one batch (fmap_b ~4.2MB ~ one XCD L2) per XCD
  const int b  = blockIdx.x & 7;
  const int oi = blockIdx.x >> 3;
  const float* fmapb = fmap + (size_t)b * (128 * 128 * 64);

  // ---- Phase 0 (wave-local): coords/coeffs for this wave's 32 px x 3 di ----
  #pragma unroll
  for (int it = 0; it < 2; ++it) {
    int e = lane + 64 * it;
    if (e < 96) {
      int di  = e >> 5;
      int upl = e & 31;
      int up  = wave * 32 + upl;
      int u   = di * 128 + up;
      int j   = u / 3;
      int a   = u - j * 3;
      const float4* yp = reinterpret_cast<const float4*>(
          y2 + ((size_t)(b * 128 + oi) * 128 + j) * 8);
      float4 xv = yp[0];
      float4 yv = yp[1];

      float hi01 = fmaxf(xv.x, xv.y), lo01 = fminf(xv.x, xv.y);
      float hi23 = fmaxf(xv.z, xv.w), lo23 = fminf(xv.z, xv.w);
      float top1 = fmaxf(hi01, hi23);
      float top2 = fmaxf(fminf(hi01, hi23), (hi01 >= hi23) ? lo01 : lo23);
      float w = fminf(fmaxf(top1, 1.f), 127.f) + fminf(fmaxf(top2, 1.f), 127.f);

      hi01 = fmaxf(yv.x, yv.y); lo01 = fminf(yv.x, yv.y);
      hi23 = fmaxf(yv.z, yv.w); lo23 = fminf(yv.z, yv.w);
      top1 = fmaxf(hi01, hi23);
      top2 = fmaxf(fminf(hi01, hi23), (hi01 >= hi23) ? lo01 : lo23);
      float h = fminf(fmaxf(top1, 1.f), 127.f) + fminf(fmaxf(top2, 1.f), 127.f);

      float x, yy;
      if (a == 0)      { x = ((float)j - 1.0f) - w / 3.0f;  yy = ((float)oi - 1.0f) - h / 3.0f; }
      else if (a == 1) { x = (float)j + w * 1e-10f;         yy = (float)oi + h * 1e-10f; }
      else             { x = ((float)j + 1.0f) + w / 3.0f;  yy = ((float)oi + 1.0f) + h / 3.0f; }

      float xl = fminf(fmaxf(floorf(x), 0.f), 127.f);
      float xr = fminf(fmaxf(ceilf(x),  0.f), 127.f);
      float yt = fminf(fmaxf(floorf(yy), 0.f), 127.f);
      float yb = fminf(fmaxf(ceilf(yy),  0.f), 127.f);
      int ixl = (int)xl, ixr = (int)xr, iyt = (int)yt, iyb = (int)yb;
      float xr_x = xr - x, xl_x = x - xl, yt_y = yy - yt, yb_y = yb - yy;
      bool need = ((xr_x != 0.f) || (xl_x != 0.f)) &&
                  ((yb_y != 0.f) || (yt_y != 0.f));
      int base_lt = (iyt * 128 + ixl) * 64;
      s_addr4[u] = make_int4(need ? base_lt : -1,
                             (iyt * 128 + ixr) * 64,
                             (iyb * 128 + ixl) * 64,
                             (iyb * 128 + ixr) * 64);
      s_cf[u] = make_float4(xr_x * yb_y, xr_x * yt_y, xl_x * yb_y, xl_x * yt_y);
    }
  }
  __builtin_amdgcn_wave_barrier();

  const int px15 = lane & 15;
  const int cgrp = lane >> 4;

  f32x4 acc[2][4];
  #pragma unroll
  for (int j = 0; j < 4; ++j) {
    float bv = biasg[j * 16 + px15];
    acc[0][j] = (f32x4){bv, bv, bv, bv};
    acc[1][j] = (f32x4){bv, bv, bv, bv};
  }

  unsigned int* stw = &stage[wave][0];

  for (int di = 0; di < 3; ++di) {
    bf16x8 Bf[8];
    #pragma unroll
    for (int jk = 0; jk < 8; ++jk)
      Bf[jk] = __builtin_bit_cast(bf16x8, wsBq[(di * 8 + jk) * 64 + lane]);

    #pragma unroll
    for (int p = 0; p < 2; ++p) {
      #pragma unroll
      for (int ks = 0; ks < 2; ++ks) {
        // ---- ISSUE: 32 fire-and-forget row loads (16 px x 2 y-rows) ----
        const float* gb = fmapb + ks * 32 + (lane & 31);
        #pragma unroll 4
        for (int pxl = 0; pxl < 16; ++pxl) {
          int u = di * 128 + wave * 32 + p * 16 + pxl;
          int4 A = s_addr4[u];
          if (A.x >= 0) {
            int offT = (lane < 32) ? A.x : A.y;   // y_top: xl | xr
            int offB = (lane < 32) ? A.z : A.w;   // y_bot: xl | xr
            gload_lds4(gb + offT, stw + (2 * pxl + 0) * 68);
            gload_lds4(gb + offB, stw + (2 * pxl + 1) * 68);
          }
        }
        asm volatile("s_waitcnt vmcnt(0)" ::: "memory");
        __builtin_amdgcn_sched_barrier(0);

        // ---- CONSUME: per-lane fragment assembly from staged rows ----
        f32x4 cf4 = *reinterpret_cast<const f32x4*>(
            &s_cf[di * 128 + wave * 32 + p * 16 + px15]);
        const int base = 2 * px15 * 68 + 4 * cgrp;
        f32x4 LT0 = *reinterpret_cast<const f32x4*>(&stw[base]);
        f32x4 RT0 = *reinterpret_cast<const f32x4*>(&stw[base + 32]);
        f32x4 LB0 = *reinterpret_cast<const f32x4*>(&stw[base + 68]);
        f32x4 RB0 = *reinterpret_cast<const f32x4*>(&stw[base + 68 + 32]);
        f32x4 LT1 = *reinterpret_cast<const f32x4*>(&stw[base + 16]);
        f32x4 RT1 = *reinterpret_cast<const f32x4*>(&stw[base + 16 + 32]);
        f32x4 LB1 = *reinterpret_cast<const f32x4*>(&stw[base + 16 + 68]);
        f32x4 RB1 = *reinterpret_cast<const f32x4*>(&stw[base + 16 + 68 + 32]);
        f32x4 vh0 = cf4[0] * LT0 + cf4[1] * RT0 + cf4[2] * LB0 + cf4[3] * RB0;
        f32x4 vh1 = cf4[0] * LT1 + cf4[1] * RT1 + cf4[2] * LB1 + cf4[3] * RB1;

        uint4 aq;
        aq.x = (unsigned)f2bf(vh0[0]) | ((unsigned)f2bf(vh0[1]) << 16);
        aq.y = (unsigned)f2bf(vh0[2]) | ((unsigned)f2bf(vh0[3]) << 16);
        aq.z = (unsigned)f2bf(vh1[0]) | ((unsigned)f2bf(vh1[1]) << 16);
        aq.w = (unsigned)f2bf(vh1[2]) | ((unsigned)f2bf(vh1[3]) << 16);
        bf16x8 a = __builtin_bit_cast(bf16x8, aq);
        #pragma unroll
        for (int j = 0; j < 4; ++j)
          acc[p][j] = __builtin_amdgcn_mfma_f32_16x16x32_bf16(a, Bf[j * 2 + ks],
                                                              acc[p][j], 0, 0, 0);
      }
    }
  }

  // ---- Epilogue: ReLU (bias pre-folded); C/D: col=lane&15, row=(lane>>4)*4+reg ----
  float* outb = out + ((size_t)(b * 128 + oi) * 128) * 64;
  #pragma unroll
  for (int p = 0; p < 2; ++p) {
    int pxB = (wave * 2 + p) * 16 + (lane >> 4) * 4;
    #pragma unroll
    for (int j = 0; j < 4; ++j) {
      int fch = j * 16 + px15;
      #pragma unroll
      for (int reg = 0; reg < 4; ++reg) {
        outb[(size_t)(pxB + reg) * 64 + fch] = fmaxf(acc[p][j][reg], 0.f);
      }
    }
  }
}

extern "C" void kernel_launch(void* const* d_in, const int* in_sizes, int n_in,
                              void* d_out, int out_size, void* d_ws, size_t ws_size,
                              hipStream_t stream) {
  const float* fmap   = (const float*)d_in[0];
  const float* y2     = (const float*)d_in[1];
  const float* conv_w = (const float*)d_in[2];
  const float* gamma  = (const float*)d_in[3];
  const float* beta   = (const float*)d_in[4];
  const float* mean   = (const float*)d_in[5];
  const float* var    = (const float*)d_in[6];
  float* outp = (float*)d_out;

  unsigned short* wsB = (unsigned short*)d_ws;
  float* bias = (float*)((char*)d_ws + 24576);

  prep_kernel<<<48, 256, 0, stream>>>(conv_w, gamma, beta, mean, var, wsB, bias);
  main_kernel<<<1024, 256, 0, stream>>>(fmap, y2, (const uint4*)d_ws, bias, outp);
}

// Round 11
// 44.175 us; speedup vs baseline: 1.3535x; 1.3535x over previous
//
#include <hip/hip_runtime.h>

typedef __bf16 bf16x8 __attribute__((ext_vector_type(8)));
typedef float f32x4 __attribute__((ext_vector_type(4)));
typedef unsigned short u16x8 __attribute__((ext_vector_type(8)));

__device__ __forceinline__ unsigned short f2bf(float f) {
  __bf16 h = (__bf16)f;
  return __builtin_bit_cast(unsigned short, h);
}
__device__ __forceinline__ float bf2f(unsigned short u) {
  return __builtin_bit_cast(float, (unsigned)u << 16);
}

// d_ws layout: [0, 24576): wsB bf16 fragment-ordered (12288 shorts)
//              [24576, 24832): bias (64 floats)
//              [32768, 32768+16777216): bf16 fmap copy (bf16 path only)
// wsB flat idx = (((di*4 + jblk)*2 + kstep)*64 + lane)*8 + i
//   mode 1 (bf16 main): c = kstep*32 + 8*(lane>>4) + i   (lane's 8ch contiguous)
//   mode 0 (fp32 main): c = kstep*32 + 4*(lane>>4) + (i&3) + 16*(i>>2)
//   fch = jblk*16 + (lane&15)
// A uses the same (lane,i)->c bijection in each mode, so both are correct.
__global__ __launch_bounds__(256) void prep_kernel(
    const float* __restrict__ conv_w, const float* __restrict__ gamma,
    const float* __restrict__ beta, const float* __restrict__ mean,
    const float* __restrict__ var, unsigned short* __restrict__ wsB,
    float* __restrict__ bias, int mode) {
  int idx = blockIdx.x * 256 + threadIdx.x;
  if (idx >= 12288) return;
  int di    = idx >> 12;
  int r     = idx & 4095;
  int jblk  = r >> 10;
  int r2    = r & 1023;
  int kstep = r2 >> 9;
  int r3    = r2 & 511;
  int lane  = r3 >> 3;
  int i     = r3 & 7;
  int c = mode ? (kstep * 32 + 8 * (lane >> 4) + i)
               : (kstep * 32 + 4 * (lane >> 4) + (i & 3) + 16 * (i >> 2));
  int fch = jblk * 16 + (lane & 15);
  float s = gamma[fch] * rsqrtf(var[fch] + 1e-3f);
  float v = conv_w[((di * 3 + 0) * 64 + c) * 64 + fch]
          + conv_w[((di * 3 + 1) * 64 + c) * 64 + fch]
          + conv_w[((di * 3 + 2) * 64 + c) * 64 + fch];
  wsB[idx] = f2bf(v * s);
  if (idx < 64) bias[idx] = beta[idx] - mean[idx] * (gamma[idx] * rsqrtf(var[idx] + 1e-3f));
}

// fmap fp32 -> bf16 copy (8.4M elements, 8/thread, fully coalesced).
__global__ __launch_bounds__(256) void cvt_kernel(
    const float* __restrict__ f, unsigned short* __restrict__ o) {
  size_t idx = (size_t)blockIdx.x * 256 + threadIdx.x;
  const float4* s = reinterpret_cast<const float4*>(f) + idx * 2;
  float4 a = s[0], b4 = s[1];
  u16x8 v;
  v[0] = f2bf(a.x);  v[1] = f2bf(a.y);  v[2] = f2bf(a.z);  v[3] = f2bf(a.w);
  v[4] = f2bf(b4.x); v[5] = f2bf(b4.y); v[6] = f2bf(b4.z); v[7] = f2bf(b4.w);
  reinterpret_cast<u16x8*>(o)[idx] = v;
}

// Shared phase-0 body: computes s_addr4 (corner element offsets) and s_cf
// (per-corner coefficients a_lt,a_rt,a_lb,a_rb) for this wave's 32 px x 3 di.
#define PHASE0_BODY(S_ADDR, S_CF)                                             \
  for (int it = 0; it < 2; ++it) {                                            \
    int e = lane + 64 * it;                                                   \
    if (e < 96) {                                                             \
      int di  = e >> 5;                                                       \
      int upl = e & 31;                                                       \
      int up  = wave * 32 + upl;                                              \
      int u   = di * 128 + up;                                                \
      int j   = u / 3;                                                        \
      int a   = u - j * 3;                                                    \
      const float4* yp = reinterpret_cast<const float4*>(                     \
          y2 + ((size_t)(b * 128 + oi) * 128 + j) * 8);                       \
      float4 xv = yp[0];                                                      \
      float4 yv = yp[1];                                                      \
      float hi01 = fmaxf(xv.x, xv.y), lo01 = fminf(xv.x, xv.y);               \
      float hi23 = fmaxf(xv.z, xv.w), lo23 = fminf(xv.z, xv.w);               \
      float top1 = fmaxf(hi01, hi23);                                         \
      float top2 = fmaxf(fminf(hi01, hi23), (hi01 >= hi23) ? lo01 : lo23);    \
      float w = fminf(fmaxf(top1, 1.f), 127.f) + fminf(fmaxf(top2, 1.f), 127.f); \
      hi01 = fmaxf(yv.x, yv.y); lo01 = fminf(yv.x, yv.y);                     \
      hi23 = fmaxf(yv.z, yv.w); lo23 = fminf(yv.z, yv.w);                     \
      top1 = fmaxf(hi01, hi23);                                               \
      top2 = fmaxf(fminf(hi01, hi23), (hi01 >= hi23) ? lo01 : lo23);          \
      float h = fminf(fmaxf(top1, 1.f), 127.f) + fminf(fmaxf(top2, 1.f), 127.f); \
      float x, yy;                                                            \
      if (a == 0)      { x = ((float)j - 1.0f) - w / 3.0f;  yy = ((float)oi - 1.0f) - h / 3.0f; } \
      else if (a == 1) { x = (float)j + w * 1e-10f;         yy = (float)oi + h * 1e-10f; } \
      else             { x = ((float)j + 1.0f) + w / 3.0f;  yy = ((float)oi + 1.0f) + h / 3.0f; } \
      float xl = fminf(fmaxf(floorf(x), 0.f), 127.f);                         \
      float xr = fminf(fmaxf(ceilf(x),  0.f), 127.f);                         \
      float yt = fminf(fmaxf(floorf(yy), 0.f), 127.f);                        \
      float yb = fminf(fmaxf(ceilf(yy),  0.f), 127.f);                        \
      int ixl = (int)xl, ixr = (int)xr, iyt = (int)yt, iyb = (int)yb;         \
      float xr_x = xr - x, xl_x = x - xl, yt_y = yy - yt, yb_y = yb - yy;     \
      S_ADDR[u] = make_int4((iyt * 128 + ixl) * 64, (iyt * 128 + ixr) * 64,   \
                            (iyb * 128 + ixl) * 64, (iyb * 128 + ixr) * 64);  \
      S_CF[u] = make_float4(xr_x * yb_y, xr_x * yt_y, xl_x * yb_y, xl_x * yt_y); \
    }                                                                         \
  }

// ---------- bf16 path: in-register fragments, 1 line per corner ----------
__global__ __launch_bounds__(256) void main_kernel_bf16(
    const unsigned short* __restrict__ fb16, const float* __restrict__ y2,
    const uint4* __restrict__ wsBq, const float* __restrict__ biasg,
    float* __restrict__ out) {
  __shared__ int4   s_addr4[384];
  __shared__ float4 s_cf[384];

  const int t    = threadIdx.x;
  const int lane = t & 63;
  const int wave = t >> 6;
  const int b  = blockIdx.x & 7;       // XCD pinning: one batch per XCD
  const int oi = blockIdx.x >> 3;
  const unsigned short* fbb = fb16 + (size_t)b * (128 * 128 * 64);

  #pragma unroll
  PHASE0_BODY(s_addr4, s_cf)
  __builtin_amdgcn_wave_barrier();

  const int px15 = lane & 15;
  const int cgrp = lane >> 4;

  f32x4 acc[2][4];
  #pragma unroll
  for (int j = 0; j < 4; ++j) {
    float bv = biasg[j * 16 + px15];
    acc[0][j] = (f32x4){bv, bv, bv, bv};
    acc[1][j] = (f32x4){bv, bv, bv, bv};
  }

  #pragma unroll 1
  for (int di = 0; di < 3; ++di) {
    bf16x8 Bf[8];
    #pragma unroll
    for (int jk = 0; jk < 8; ++jk)
      Bf[jk] = __builtin_bit_cast(bf16x8, wsBq[(di * 8 + jk) * 64 + lane]);

    #pragma unroll
    for (int p = 0; p < 2; ++p) {
      const int u = di * 128 + wave * 32 + p * 16 + px15;
      f32x4 cf;
      {
        float4 c4 = s_cf[u];
        cf = (f32x4){c4.x, c4.y, c4.z, c4.w};
      }
      int4 A = s_addr4[u];
      bool need = (cf[0] != 0.f) || (cf[1] != 0.f) || (cf[2] != 0.f) || (cf[3] != 0.f);

      #pragma unroll
      for (int ks = 0; ks < 2; ++ks) {
        const int choff = ks * 32 + 8 * cgrp;   // lane's 8 contiguous channels
        u16x8 lt = {0,0,0,0,0,0,0,0}, rt = {0,0,0,0,0,0,0,0};
        u16x8 lb = {0,0,0,0,0,0,0,0}, rb = {0,0,0,0,0,0,0,0};
        if (need) {
          lt = *reinterpret_cast<const u16x8*>(fbb + A.x + choff);
          rt = *reinterpret_cast<const u16x8*>(fbb + A.y + choff);
          lb = *reinterpret_cast<const u16x8*>(fbb + A.z + choff);
          rb = *reinterpret_cast<const u16x8*>(fbb + A.w + choff);
        }
        unsigned aw0, aw1, aw2, aw3;
        {
          float e0 = cf[0]*bf2f(lt[0]) + cf[1]*bf2f(rt[0]) + cf[2]*bf2f(lb[0]) + cf[3]*bf2f(rb[0]);
          float e1 = cf[0]*bf2f(lt[1]) + cf[1]*bf2f(rt[1]) + cf[2]*bf2f(lb[1]) + cf[3]*bf2f(rb[1]);
          float e2 = cf[0]*bf2f(lt[2]) + cf[1]*bf2f(rt[2]) + cf[2]*bf2f(lb[2]) + cf[3]*bf2f(rb[2]);
          float e3 = cf[0]*bf2f(lt[3]) + cf[1]*bf2f(rt[3]) + cf[2]*bf2f(lb[3]) + cf[3]*bf2f(rb[3]);
          float e4 = cf[0]*bf2f(lt[4]) + cf[1]*bf2f(rt[4]) + cf[2]*bf2f(lb[4]) + cf[3]*bf2f(rb[4]);
          float e5 = cf[0]*bf2f(lt[5]) + cf[1]*bf2f(rt[5]) + cf[2]*bf2f(lb[5]) + cf[3]*bf2f(rb[5]);
          float e6 = cf[0]*bf2f(lt[6]) + cf[1]*bf2f(rt[6]) + cf[2]*bf2f(lb[6]) + cf[3]*bf2f(rb[6]);
          float e7 = cf[0]*bf2f(lt[7]) + cf[1]*bf2f(rt[7]) + cf[2]*bf2f(lb[7]) + cf[3]*bf2f(rb[7]);
          aw0 = (unsigned)f2bf(e0) | ((unsigned)f2bf(e1) << 16);
          aw1 = (unsigned)f2bf(e2) | ((unsigned)f2bf(e3) << 16);
          aw2 = (unsigned)f2bf(e4) | ((unsigned)f2bf(e5) << 16);
          aw3 = (unsigned)f2bf(e6) | ((unsigned)f2bf(e7) << 16);
        }
        uint4 aqv = make_uint4(aw0, aw1, aw2, aw3);
        bf16x8 a = __builtin_bit_cast(bf16x8, aqv);
        #pragma unroll
        for (int j = 0; j < 4; ++j)
          acc[p][j] = __builtin_amdgcn_mfma_f32_16x16x32_bf16(a, Bf[j * 2 + ks],
                                                              acc[p][j], 0, 0, 0);
      }
    }
  }

  float* outb = out + ((size_t)(b * 128 + oi) * 128) * 64;
  #pragma unroll
  for (int p = 0; p < 2; ++p) {
    int pxB = (wave * 2 + p) * 16 + (lane >> 4) * 4;
    #pragma unroll
    for (int j = 0; j < 4; ++j) {
      int fch = j * 16 + px15;
      #pragma unroll
      for (int reg = 0; reg < 4; ++reg) {
        outb[(size_t)(pxB + reg) * 64 + fch] = fmaxf(acc[p][j][reg], 0.f);
      }
    }
  }
}

// ---------- fp32 fallback (R5 structure; used only if ws_size too small) ----------
__global__ __launch_bounds__(256, 4) void main_kernel_fp32(
    const float* __restrict__ fmap, const float* __restrict__ y2,
    const uint4* __restrict__ wsBq, const float* __restrict__ biasg,
    float* __restrict__ out) {
  __shared__ int4   s_addr4[384];
  __shared__ float4 s_cf[384];
  __shared__ uint2  fsA[4][4][64][2];

  const int t    = threadIdx.x;
  const int lane = t & 63;
  const int wave = t >> 6;
  const int b  = blockIdx.x & 7;
  const int oi = blockIdx.x >> 3;
  const float* fmapb = fmap + (size_t)b * (128 * 128 * 64);

  #pragma unroll
  PHASE0_BODY(s_addr4, s_cf)
  __builtin_amdgcn_wave_barrier();

  const int px15 = lane & 15;
  const int cg   = lane & 15;
  const int g    = cg & 3;
  const int hh   = (cg >> 2) & 1;
  const int ksS  = cg >> 3;
  const int upg  = lane >> 4;
  const int lsr  = lane ^ (2 * (lane >> 4));
  const int c0   = cg * 4;

  f32x4 acc[2][4];
  #pragma unroll
  for (int j = 0; j < 4; ++j) {
    float bv = biasg[j * 16 + px15];
    acc[0][j] = (f32x4){bv, bv, bv, bv};
    acc[1][j] = (f32x4){bv, bv, bv, bv};
  }

  for (int di = 0; di < 3; ++di) {
    bf16x8 Bf[8];
    #pragma unroll
    for (int jk = 0; jk < 8; ++jk)
      Bf[jk] = __builtin_bit_cast(bf16x8, wsBq[(di * 8 + jk) * 64 + lane]);

    #pragma unroll 4
    for (int r = 0; r < 8; ++r) {
      int upl = r * 4 + upg;
      int u   = di * 128 + wave * 32 + upl;
      float4 cf = s_cf[u];
      bool need = (cf.x != 0.f) || (cf.y != 0.f) || (cf.z != 0.f) || (cf.w != 0.f);
      uint2 q = make_uint2(0u, 0u);
      if (need) {
        int4 A = s_addr4[u];
        float4 lt = *reinterpret_cast<const float4*>(fmapb + A.x + c0);
        float4 rt = *reinterpret_cast<const float4*>(fmapb + A.y + c0);
        float4 lb = *reinterpret_cast<const float4*>(fmapb + A.z + c0);
        float4 rb = *reinterpret_cast<const float4*>(fmapb + A.w + c0);
        float v0 = cf.x * lt.x + cf.y * rt.x + cf.z * lb.x + cf.w * rb.x;
        float v1 = cf.x * lt.y + cf.y * rt.y + cf.z * lb.y + cf.w * rb.y;
        float v2 = cf.x * lt.z + cf.y * rt.z + cf.z * lb.z + cf.w * rb.z;
        float v3 = cf.x * lt.w + cf.y * rt.w + cf.z * lb.w + cf.w * rb.w;
        q.x = (unsigned)f2bf(v0) | ((unsigned)f2bf(v1) << 16);
        q.y = (unsigned)f2bf(v2) | ((unsigned)f2bf(v3) << 16);
      }
      int lpp = ((upl & 15) | (g << 4)) ^ (g << 1);
      fsA[wave][(upl >> 4) * 2 + ksS][lpp][hh] = q;
    }
    __builtin_amdgcn_wave_barrier();

    #pragma unroll
    for (int ks = 0; ks < 2; ++ks) {
      #pragma unroll
      for (int p = 0; p < 2; ++p) {
        bf16x8 a = __builtin_bit_cast(bf16x8,
            *reinterpret_cast<const uint4*>(&fsA[wave][p * 2 + ks][lsr][0]));
        #pragma unroll
        for (int j = 0; j < 4; ++j)
          acc[p][j] = __builtin_amdgcn_mfma_f32_16x16x32_bf16(a, Bf[j * 2 + ks],
                                                              acc[p][j], 0, 0, 0);
      }
    }
    __builtin_amdgcn_wave_barrier();
  }

  float* outb = out + ((size_t)(b * 128 + oi) * 128) * 64;
  #pragma unroll
  for (int p = 0; p < 2; ++p) {
    int pxB = (wave * 2 + p) * 16 + (lane >> 4) * 4;
    #pragma unroll
    for (int j = 0; j < 4; ++j) {
      int fch = j * 16 + px15;
      #pragma unroll
      for (int reg = 0; reg < 4; ++reg) {
        outb[(size_t)(pxB + reg) * 64 + fch] = fmaxf(acc[p][j][reg], 0.f);
      }
    }
  }
}

extern "C" void kernel_launch(void* const* d_in, const int* in_sizes, int n_in,
                              void* d_out, int out_size, void* d_ws, size_t ws_size,
                              hipStream_t stream) {
  const float* fmap   = (const float*)d_in[0];
  const float* y2     = (const float*)d_in[1];
  const float* conv_w = (const float*)d_in[2];
  const float* gamma  = (const float*)d_in[3];
  const float* beta   = (const float*)d_in[4];
  const float* mean   = (const float*)d_in[5];
  const float* var    = (const float*)d_in[6];
  float* outp = (float*)d_out;

  unsigned short* wsB  = (unsigned short*)d_ws;
  float* bias          = (float*)((char*)d_ws + 24576);
  unsigned short* fb16 = (unsigned short*)((char*)d_ws + 32768);

  const bool big = ws_size >= (size_t)(18u * 1024u * 1024u);
  if (big) {
    prep_kernel<<<48, 256, 0, stream>>>(conv_w, gamma, beta, mean, var, wsB, bias, 1);
    cvt_kernel<<<4096, 256, 0, stream>>>(fmap, fb16);
    main_kernel_bf16<<<1024, 256, 0, stream>>>(fb16, y2, (const uint4*)d_ws, bias, outp);
  } else {
    prep_kernel<<<48, 256, 0, stream>>>(conv_w, gamma, beta, mean, var, wsB, bias, 0);
    main_kernel_fp32<<<1024, 256, 0, stream>>>(fmap, y2, (const uint4*)d_ws, bias, outp);
  }
}